// Round 14
// baseline (224.651 us; speedup 1.0000x reference)
//
#include <hip/hip_runtime.h>
#include <hip/hip_fp16.h>

// SparseGraphWaveletLayer: out = relu( (phi·diag(theta)) @ (phi_inv @ (F_sparse @ W)) )
// N=50000, IN_CH=256, OUT_CH=128, NNZ=800000 per sparse matrix.
//
// Round 13 -> 14 (build-phase cuts; spmm unchanged):
//  - eb compressed 8 -> 6 B/edge as split arrays: key u32 = col|rowlow<<16,
//    val u16 = fp16 (conversion moved to phase C). Scatter write and phase-D
//    read drop 19.2 -> 14.4 MB; scatter LDS staging 36 -> 28 KB.
//  - wave-privatized LDS histograms (4 copies) in phases A/C/D: 16-way ->
//    4-way same-bin atomic contention.

#define OUT_CH 128
#define HALF_CH 64
#define RPB 256           // rows per bucket
#define RPB_SHIFT 8
#define MAX_NB 256        // supports N <= 65536
#define EPB 4096          // edges per block in phases A/C (256 thr x 16)
#define EPT 16            // edges per thread in phase C
#define MAX_CHUNK 16      // supports NBLK <= 1024
#define STAGE_CAP 8192    // phase-D LDS staging capacity (32KB of u32)

// ---------------- Phase A: per-block bucket histograms (wave-privatized) ----

__global__ __launch_bounds__(256) void bucket_hist_kernel(
    const int* __restrict__ rows0, int n0,
    const int* __restrict__ rows1, int n1,
    const int* __restrict__ rows2, int n2,
    int* __restrict__ hist_part,        // [3][NBLK][NB]
    int NB, int NBLK)
{
    int m = blockIdx.y;
    const int* rows = (m == 0) ? rows0 : (m == 1) ? rows1 : rows2;
    int nnz         = (m == 0) ? n0    : (m == 1) ? n1    : n2;
    __shared__ int bins[4][MAX_NB];
    int t = threadIdx.x;
    int wid = t >> 6;
    for (int i = t; i < 4 * MAX_NB; i += 256) ((int*)bins)[i] = 0;
    __syncthreads();
    int base = blockIdx.x * EPB;
    #pragma unroll 4
    for (int k = 0; k < EPB / 256; ++k) {
        int i = base + k * 256 + t;
        if (i < nnz) atomicAdd(&bins[wid][rows[i] >> RPB_SHIFT], 1);
    }
    __syncthreads();
    int* out = hist_part + ((size_t)(m * NBLK + blockIdx.x)) * NB;
    if (t < NB) out[t] = bins[0][t] + bins[1][t] + bins[2][t] + bins[3][t];
}

// ---------------- Phase B1: wave-per-(m,bucket) scan over blocks ------------

__global__ __launch_bounds__(256) void scan_blocks_wave_kernel(
    int* __restrict__ hist_part, int* __restrict__ totals, int NB, int NBLK)
{
    int w = blockIdx.x * 4 + (threadIdx.x >> 6);
    if (w >= 3 * NB) return;
    int lane = threadIdx.x & 63;
    int m = w / NB, b = w - m * NB;
    const int chunk = (NBLK + 63) >> 6;
    int base_blk = lane * chunk;

    int v[MAX_CHUNK];
    int sum = 0;
    for (int k = 0; k < chunk; ++k) {
        int blk = base_blk + k;
        int x = (blk < NBLK) ? hist_part[((size_t)(m * NBLK + blk)) * NB + b] : 0;
        v[k] = x; sum += x;
    }
    int incl = sum;
    #pragma unroll
    for (int s = 1; s < 64; s <<= 1) {
        int y = __shfl_up(incl, s);
        if (lane >= s) incl += y;
    }
    int run = incl - sum;                 // lane-exclusive prefix
    for (int k = 0; k < chunk; ++k) {
        int blk = base_blk + k;
        if (blk < NBLK) {
            hist_part[((size_t)(m * NBLK + blk)) * NB + b] = run;
            run += v[k];
        }
    }
    if (lane == 63) totals[w] = incl;
}

// ---------------- Phase B2: exclusive scan over buckets per matrix ----------

__global__ __launch_bounds__(1024) void scan_buckets_kernel(
    const int* __restrict__ totals, int* __restrict__ bases, int NB)
{
    int m = blockIdx.x;
    int t = threadIdx.x;
    int x = (t < NB) ? totals[m * NB + t] : 0;
    int lane = t & 63, wid = t >> 6;
    int incl = x;
    #pragma unroll
    for (int s = 1; s < 64; s <<= 1) {
        int y = __shfl_up(incl, s);
        if (lane >= s) incl += y;
    }
    __shared__ int wtot[16];
    __shared__ int wbase[16];
    if (lane == 63) wtot[wid] = incl;
    __syncthreads();
    if (t == 0) {
        int run = 0;
        #pragma unroll
        for (int w = 0; w < 16; ++w) { int v = wtot[w]; wbase[w] = run; run += v; }
    }
    __syncthreads();
    if (t < NB) bases[m * NB + t] = wbase[wid] + incl - x;
}

// ---------------- Phase C: LDS-staged bucket scatter (compressed out) -------
// Writes split compressed edges: key u32 = col | rowlow<<16, val u16 = fp16.
// theta folded into matrix 2.

__global__ __launch_bounds__(256) void bucket_scatter_kernel(
    const int* __restrict__ rows0, const int* __restrict__ cols0, const float* __restrict__ vals0, int n0,
    const int* __restrict__ rows1, const int* __restrict__ cols1, const float* __restrict__ vals1, int n1,
    const int* __restrict__ rows2, const int* __restrict__ cols2, const float* __restrict__ vals2, int n2,
    const float* __restrict__ theta,
    const int* __restrict__ hist_part, const int* __restrict__ bases,
    unsigned int* __restrict__ ek0, unsigned int* __restrict__ ek1, unsigned int* __restrict__ ek2,
    unsigned short* __restrict__ ev0, unsigned short* __restrict__ ev1, unsigned short* __restrict__ ev2,
    int NB, int NBLK)
{
    int m = blockIdx.y;
    const int* rows; const int* cols; const float* vals; int nnz;
    unsigned int* ek; unsigned short* ev;
    if (m == 0)      { rows = rows0; cols = cols0; vals = vals0; nnz = n0; ek = ek0; ev = ev0; }
    else if (m == 1) { rows = rows1; cols = cols1; vals = vals1; nnz = n1; ek = ek1; ev = ev1; }
    else             { rows = rows2; cols = cols2; vals = vals2; nnz = n2; ek = ek2; ev = ev2; }

    __shared__ unsigned int   skey[EPB];       // 16 KB
    __shared__ unsigned short sval[EPB];       // 8 KB
    __shared__ unsigned char  bucket_of[EPB];  // 4 KB
    __shared__ int lhist[4][MAX_NB];           // 4 KB
    __shared__ int lstart[MAX_NB];
    __shared__ int lcur[MAX_NB];
    __shared__ int gbase[MAX_NB];
    __shared__ int wtot[4], wbase[4];

    int t = threadIdx.x;
    int wid = t >> 6;
    for (int i = t; i < 4 * MAX_NB; i += 256) ((int*)lhist)[i] = 0;
    __syncthreads();

    int base = blockIdx.x * EPB;
    bool fold = (m == 2);

    int bk[EPT];
    unsigned int   pk[EPT];
    unsigned short pv[EPT];
    #pragma unroll
    for (int k = 0; k < EPT; ++k) {
        int i = base + k * 256 + t;
        if (i < nnz) {
            int r = rows[i], c = cols[i];
            float v = vals[i];
            if (fold) v *= theta[c];
            bk[k] = r >> RPB_SHIFT;
            pk[k] = (unsigned int)c | ((unsigned int)(r & (RPB - 1)) << 16);
            pv[k] = __half_as_ushort(__float2half_rn(v));
            atomicAdd(&lhist[wid][bk[k]], 1);
        } else bk[k] = -1;
    }
    __syncthreads();

    {   // block exclusive scan of NB (<=256) merged counts
        int x = 0;
        if (t < NB) x = lhist[0][t] + lhist[1][t] + lhist[2][t] + lhist[3][t];
        int lane = t & 63;
        int incl = x;
        #pragma unroll
        for (int s = 1; s < 64; s <<= 1) {
            int y = __shfl_up(incl, s);
            if (lane >= s) incl += y;
        }
        if (lane == 63) wtot[wid] = incl;
        __syncthreads();
        if (t == 0) {
            int run = 0;
            #pragma unroll
            for (int w = 0; w < 4; ++w) { int v = wtot[w]; wbase[w] = run; run += v; }
        }
        __syncthreads();
        if (t < NB) {
            int excl = wbase[wid] + incl - x;
            lstart[t] = excl;
            lcur[t]   = excl;
            const int* hp = hist_part + ((size_t)(m * NBLK + blockIdx.x)) * NB;
            gbase[t] = bases[m * NB + t] + hp[t];
        }
    }
    __syncthreads();

    #pragma unroll
    for (int k = 0; k < EPT; ++k) {
        if (bk[k] >= 0) {
            int idx = atomicAdd(&lcur[bk[k]], 1);     // LDS atomic
            skey[idx] = pk[k];
            sval[idx] = pv[k];
            bucket_of[idx] = (unsigned char)bk[k];
        }
    }
    __syncthreads();

    int count = min(EPB, nnz - base);
    for (int i = t; i < count; i += 256) {
        int b = bucket_of[i];
        int dest = gbase[b] + (i - lstart[b]);
        ek[dest] = skey[i];
        ev[dest] = sval[i];
    }
}

// ---------------- Phase D: bucket -> row-sorted compressed CSR + off --------
// ec entry: col(u16) | fp16(val)<<16. LDS-staged sequential writeback.

__global__ __launch_bounds__(256) void bucket_to_csr_kernel(
    const unsigned int* __restrict__ ek0, const unsigned int* __restrict__ ek1, const unsigned int* __restrict__ ek2,
    const unsigned short* __restrict__ ev0, const unsigned short* __restrict__ ev1, const unsigned short* __restrict__ ev2,
    unsigned int* __restrict__ ec0, unsigned int* __restrict__ ec1, unsigned int* __restrict__ ec2,
    const int* __restrict__ bases,
    int* __restrict__ off,              // [3][n+1]
    int n0, int n1, int n2, int NB, int n)
{
    int m = blockIdx.y;
    int b = blockIdx.x;
    const unsigned int* ek; const unsigned short* ev; unsigned int* ec; int nnz;
    if (m == 0)      { ek = ek0; ev = ev0; ec = ec0; nnz = n0; }
    else if (m == 1) { ek = ek1; ev = ev1; ec = ec1; nnz = n1; }
    else             { ek = ek2; ev = ev2; ec = ec2; nnz = n2; }
    int base = bases[m * NB + b];
    int end  = (b + 1 < NB) ? bases[m * NB + b + 1] : nnz;
    int cnt  = end - base;

    __shared__ unsigned int staged_c[STAGE_CAP];   // 32 KB
    __shared__ int histw[4][RPB];                  // 4 KB
    __shared__ int cur[RPB];
    __shared__ int loc[RPB + 1];
    __shared__ int wtot[4];
    __shared__ int wbase[4];
    int t = threadIdx.x;
    int wid = t >> 6;
    for (int i = t; i < 4 * RPB; i += 256) ((int*)histw)[i] = 0;
    cur[t] = 0;
    __syncthreads();
    for (int i = base + t; i < end; i += 256)
        atomicAdd(&histw[wid][(ek[i] >> 16) & (RPB - 1)], 1);
    __syncthreads();
    {   // block exclusive scan of 256 merged counts
        int x = histw[0][t] + histw[1][t] + histw[2][t] + histw[3][t];
        int lane = t & 63;
        int incl = x;
        #pragma unroll
        for (int s = 1; s < 64; s <<= 1) {
            int y = __shfl_up(incl, s);
            if (lane >= s) incl += y;
        }
        if (lane == 63) wtot[wid] = incl;
        __syncthreads();
        if (t == 0) {
            int run = 0;
            #pragma unroll
            for (int w = 0; w < 4; ++w) { int v = wtot[w]; wbase[w] = run; run += v; }
        }
        __syncthreads();
        loc[t] = wbase[wid] + incl - x;
        if (t == RPB - 1) loc[RPB] = wbase[3] + incl;
    }
    __syncthreads();
    {
        int r = b * RPB + t;
        if (r <= n) off[(size_t)m * (n + 1) + r] = base + loc[t];
        if (b == NB - 1 && t == 0) off[(size_t)m * (n + 1) + n] = nnz;
    }
    if (cnt <= STAGE_CAP) {
        for (int i = base + t; i < end; i += 256) {
            unsigned int k = ek[i];
            int rl = (k >> 16) & (RPB - 1);
            int rk = atomicAdd(&cur[rl], 1);   // LDS atomic
            staged_c[loc[rl] + rk] = (k & 0xFFFFu) | ((unsigned int)ev[i] << 16);
        }
        __syncthreads();
        for (int i = t; i < cnt; i += 256)
            ec[base + i] = staged_c[i];
    } else {
        for (int i = base + t; i < end; i += 256) {
            unsigned int k = ek[i];
            int rl = (k >> 16) & (RPB - 1);
            int rk = atomicAdd(&cur[rl], 1);
            ec[base + loc[rl] + rk] = (k & 0xFFFFu) | ((unsigned int)ev[i] << 16);
        }
    }
}

// ---------------- gather-side CSR SpMM, 4B compressed edges, unroll-8 -------

template<bool SRC_H, bool DST_H, bool RELU>
__global__ __launch_bounds__(256) void spmm_csr_kernel(
    const int* __restrict__ off, const unsigned int* __restrict__ edges,
    const void* __restrict__ dense_v, void* __restrict__ out_v, int nrows)
{
    int lane = threadIdx.x & 63;
    int r = blockIdx.x * 4 + (threadIdx.x >> 6);
    if (r >= nrows) return;
    int j   = __builtin_amdgcn_readfirstlane(off[r]);
    int end = __builtin_amdgcn_readfirstlane(off[r + 1]);
    const float2*  df = (const float2*)dense_v;
    const __half2* dh = (const __half2*)dense_v;

    float2 a0 = make_float2(0.f, 0.f), a1 = make_float2(0.f, 0.f);

    for (; j + 8 <= end; j += 8) {
        unsigned int e[8]; float2 d[8];
        #pragma unroll
        for (int k = 0; k < 8; ++k) e[k] = edges[j + k];
        #pragma unroll
        for (int k = 0; k < 8; ++k) {
            if (SRC_H) d[k] = __half22float2(dh[(size_t)(e[k] & 0xFFFF) * HALF_CH + lane]);
            else       d[k] = df[(size_t)(e[k] & 0xFFFF) * HALF_CH + lane];
        }
        #pragma unroll
        for (int k = 0; k < 8; ++k) {
            float v = __half2float(__ushort_as_half((unsigned short)(e[k] >> 16)));
            if (k & 1) { a1.x = fmaf(v, d[k].x, a1.x); a1.y = fmaf(v, d[k].y, a1.y); }
            else       { a0.x = fmaf(v, d[k].x, a0.x); a0.y = fmaf(v, d[k].y, a0.y); }
        }
    }
    for (; j + 4 <= end; j += 4) {
        unsigned int e[4]; float2 d[4];
        #pragma unroll
        for (int k = 0; k < 4; ++k) e[k] = edges[j + k];
        #pragma unroll
        for (int k = 0; k < 4; ++k) {
            if (SRC_H) d[k] = __half22float2(dh[(size_t)(e[k] & 0xFFFF) * HALF_CH + lane]);
            else       d[k] = df[(size_t)(e[k] & 0xFFFF) * HALF_CH + lane];
        }
        #pragma unroll
        for (int k = 0; k < 4; ++k) {
            float v = __half2float(__ushort_as_half((unsigned short)(e[k] >> 16)));
            if (k & 1) { a1.x = fmaf(v, d[k].x, a1.x); a1.y = fmaf(v, d[k].y, a1.y); }
            else       { a0.x = fmaf(v, d[k].x, a0.x); a0.y = fmaf(v, d[k].y, a0.y); }
        }
    }
    for (; j < end; ++j) {
        unsigned int e0 = edges[j];
        float2 d0;
        if (SRC_H) d0 = __half22float2(dh[(size_t)(e0 & 0xFFFF) * HALF_CH + lane]);
        else       d0 = df[(size_t)(e0 & 0xFFFF) * HALF_CH + lane];
        float v0 = __half2float(__ushort_as_half((unsigned short)(e0 >> 16)));
        a0.x = fmaf(v0, d0.x, a0.x); a0.y = fmaf(v0, d0.y, a0.y);
    }
    float2 res = make_float2(a0.x + a1.x, a0.y + a1.y);
    if (RELU) { res.x = fmaxf(res.x, 0.f); res.y = fmaxf(res.y, 0.f); }
    if (DST_H) ((__half2*)out_v)[(size_t)r * HALF_CH + lane] = __float22half2_rn(res);
    else       ((float2*) out_v)[(size_t)r * HALF_CH + lane] = res;
}

// ---------------- fallback (round-0) atomic path ----------------

__global__ __launch_bounds__(256) void spmm_atomic_kernel(
    const int* __restrict__ rows, const int* __restrict__ cols,
    const float* __restrict__ vals, const float* __restrict__ theta,
    const float* __restrict__ dense, float* __restrict__ out, int nnz)
{
    int idx = blockIdx.x * blockDim.x + threadIdx.x;
    int e = idx >> 7;
    int f = idx & (OUT_CH - 1);
    if (e >= nnz) return;
    int r = rows[e];
    int c = cols[e];
    float v = vals[e];
    if (theta != nullptr) v *= theta[c];
    atomicAdd(&out[(size_t)r * OUT_CH + f], v * dense[(size_t)c * OUT_CH + f]);
}

__global__ __launch_bounds__(256) void relu_kernel(float* __restrict__ out, int n4)
{
    int i = blockIdx.x * blockDim.x + threadIdx.x;
    if (i >= n4) return;
    float4 v = ((float4*)out)[i];
    v.x = fmaxf(v.x, 0.f); v.y = fmaxf(v.y, 0.f);
    v.z = fmaxf(v.z, 0.f); v.w = fmaxf(v.w, 0.f);
    ((float4*)out)[i] = v;
}

// ---------------- launch ----------------

static inline size_t align16(size_t x) { return (x + 15) & ~(size_t)15; }

extern "C" void kernel_launch(void* const* d_in, const int* in_sizes, int n_in,
                              void* d_out, int out_size, void* d_ws, size_t ws_size,
                              hipStream_t stream)
{
    const int*   phi_idx   = (const int*)d_in[0];
    const float* phi_vals  = (const float*)d_in[1];
    const int*   phii_idx  = (const int*)d_in[2];
    const float* phii_vals = (const float*)d_in[3];
    const int*   feat_idx  = (const int*)d_in[4];
    const float* feat_vals = (const float*)d_in[5];
    const float* W         = (const float*)d_in[6];
    const float* theta     = (const float*)d_in[7];

    const int nnz_phi  = in_sizes[1];
    const int nnz_phii = in_sizes[3];
    const int nnz_feat = in_sizes[5];
    const int n_nodes  = in_sizes[7];
    const int in_ch    = in_sizes[6] / OUT_CH;
    const size_t dense_elems = (size_t)n_nodes * OUT_CH;
    const long long total_e = (long long)nnz_feat + nnz_phii + nnz_phi;

    const int NB = (n_nodes + RPB - 1) >> RPB_SHIFT;
    int max_nnz = nnz_feat > nnz_phii ? nnz_feat : nnz_phii;
    if (nnz_phi > max_nnz) max_nnz = nnz_phi;
    const int NBLK = (max_nnz + EPB - 1) / EPB;

    // ---- workspace layout ----
    size_t p = 0;
    size_t filtered_off = p; p += align16(dense_elems * sizeof(__half));
    size_t tmp_off      = p; p += align16(dense_elems * sizeof(__half));
    size_t off_off      = p; p += align16((size_t)3 * (n_nodes + 1) * sizeof(int));
    size_t hp_off       = p; p += align16((size_t)3 * NBLK * NB * sizeof(int));
    size_t tot_off      = p; p += align16((size_t)3 * NB * sizeof(int));
    size_t bas_off      = p; p += align16((size_t)3 * NB * sizeof(int));
    size_t ek_off       = p; p += align16((size_t)total_e * sizeof(unsigned int));
    size_t ev_off       = p; p += align16((size_t)total_e * sizeof(unsigned short));
    size_t ec_off       = p; p += align16((size_t)total_e * sizeof(unsigned int));
    size_t need = p;

    char* ws = (char*)d_ws;
    dim3 block(256);

    bool fast_ok = (ws_size >= need) && (NB <= MAX_NB) && (n_nodes <= 65536) &&
                   (in_ch <= 65536) && (NBLK <= 64 * MAX_CHUNK);

    if (fast_ok) {
        __half* filtered = (__half*)(ws + filtered_off);
        __half* tmp      = (__half*)(ws + tmp_off);
        int* off_arr    = (int*)(ws + off_off);
        int* hist_part  = (int*)(ws + hp_off);
        int* totals     = (int*)(ws + tot_off);
        int* bases      = (int*)(ws + bas_off);
        unsigned int*   ek0 = (unsigned int*)(ws + ek_off);
        unsigned int*   ek1 = ek0 + nnz_feat;
        unsigned int*   ek2 = ek1 + nnz_phii;
        unsigned short* ev0 = (unsigned short*)(ws + ev_off);
        unsigned short* ev1 = ev0 + nnz_feat;
        unsigned short* ev2 = ev1 + nnz_phii;
        unsigned int*   ec0 = (unsigned int*)(ws + ec_off);
        unsigned int*   ec1 = ec0 + nnz_feat;
        unsigned int*   ec2 = ec1 + nnz_phii;

        const int* rows0 = feat_idx;  const int* cols0 = feat_idx + nnz_feat;
        const int* rows1 = phii_idx;  const int* cols1 = phii_idx + nnz_phii;
        const int* rows2 = phi_idx;   const int* cols2 = phi_idx  + nnz_phi;

        bucket_hist_kernel<<<dim3(NBLK, 3), block, 0, stream>>>(
            rows0, nnz_feat, rows1, nnz_phii, rows2, nnz_phi,
            hist_part, NB, NBLK);

        int nwaves = 3 * NB;
        scan_blocks_wave_kernel<<<dim3((nwaves + 3) / 4), block, 0, stream>>>(
            hist_part, totals, NB, NBLK);

        scan_buckets_kernel<<<dim3(3), dim3(1024), 0, stream>>>(totals, bases, NB);

        bucket_scatter_kernel<<<dim3(NBLK, 3), block, 0, stream>>>(
            rows0, cols0, feat_vals, nnz_feat,
            rows1, cols1, phii_vals, nnz_phii,
            rows2, cols2, phi_vals,  nnz_phi,
            theta, hist_part, bases,
            ek0, ek1, ek2, ev0, ev1, ev2, NB, NBLK);

        bucket_to_csr_kernel<<<dim3(NB, 3), block, 0, stream>>>(
            ek0, ek1, ek2, ev0, ev1, ev2, ec0, ec1, ec2, bases, off_arr,
            nnz_feat, nnz_phii, nnz_phi, NB, n_nodes);

        int* off_f  = off_arr;
        int* off_pi = off_arr + (n_nodes + 1);
        int* off_p  = off_arr + 2 * (n_nodes + 1);

        dim3 grid_r((unsigned)((n_nodes + 3) / 4));
        // stage 1: src fp32 W, dst fp16 filtered
        spmm_csr_kernel<false, true, false><<<grid_r, block, 0, stream>>>(
            off_f,  ec0, (const void*)W, (void*)filtered, n_nodes);
        // stage 2: src fp16 filtered, dst fp16 tmp
        spmm_csr_kernel<true, true, false><<<grid_r, block, 0, stream>>>(
            off_pi, ec1, (const void*)filtered, (void*)tmp, n_nodes);
        // stage 3: src fp16 tmp, dst fp32 out + relu
        spmm_csr_kernel<true, false, true><<<grid_r, block, 0, stream>>>(
            off_p,  ec2, (const void*)tmp, d_out, n_nodes);
    } else {
        // fallback: round-0 atomic path (needs only 2 fp32 dense buffers)
        float* filtered = (float*)ws;
        float* tmp      = filtered + dense_elems;
        hipMemsetAsync(filtered, 0, 2 * dense_elems * sizeof(float), stream);
        hipMemsetAsync(d_out, 0, (size_t)out_size * sizeof(float), stream);
        {
            long long t = (long long)nnz_feat * OUT_CH;
            spmm_atomic_kernel<<<dim3((unsigned)((t + 255) / 256)), block, 0, stream>>>(
                feat_idx, feat_idx + nnz_feat, feat_vals, nullptr, W, filtered, nnz_feat);
        }
        {
            long long t = (long long)nnz_phii * OUT_CH;
            spmm_atomic_kernel<<<dim3((unsigned)((t + 255) / 256)), block, 0, stream>>>(
                phii_idx, phii_idx + nnz_phii, phii_vals, nullptr, filtered, tmp, nnz_phii);
        }
        {
            long long t = (long long)nnz_phi * OUT_CH;
            spmm_atomic_kernel<<<dim3((unsigned)((t + 255) / 256)), block, 0, stream>>>(
                phi_idx, phi_idx + nnz_phi, phi_vals, theta, tmp, (float*)d_out, nnz_phi);
        }
        {
            int n4 = out_size / 4;
            relu_kernel<<<dim3((n4 + 255) / 256), block, 0, stream>>>((float*)d_out, n4);
        }
    }
}

// Round 15
// 218.881 us; speedup vs baseline: 1.0264x; 1.0264x over previous
//
#include <hip/hip_runtime.h>
#include <hip/hip_fp16.h>

// SparseGraphWaveletLayer: out = relu( (phi·diag(theta)) @ (phi_inv @ (F_sparse @ W)) )
// N=50000, IN_CH=256, OUT_CH=128, NNZ=800000 per sparse matrix.
//
// Round 14 -> 15: REVERT to round-13 (best: 218.4us). Round-14's split 6B
// edge format + wave-privatized hists regressed (+6us): below ~20us/kernel
// the build phases are latency/instruction-bound, not BW-bound — byte
// shaving added stream/merge overhead instead.
//
// Final pipeline:
//   A: per-block 256-bucket LDS histograms -> dense partials (no global atomics)
//   B1/B2: wave-parallel scans -> per-(block,bucket) disjoint write ranges
//   C: LDS-staged bucket sort + coalesced run-ordered scatter (theta folded)
//   D: per-bucket row sort in LDS -> compressed CSR (col u16 | fp16 val) + off
//   SpMM x3: one wave per row, register fp32 accumulation, unroll-8 gathers,
//            fp16 intermediates (filtered/tmp), ReLU fused in stage 3.

#define OUT_CH 128
#define HALF_CH 64
#define RPB 256           // rows per bucket
#define RPB_SHIFT 8
#define MAX_NB 256        // supports N <= 65536
#define EPB 4096          // edges per block in phases A/C (256 thr x 16)
#define EPT 16            // edges per thread in phase C
#define MAX_CHUNK 16      // supports NBLK <= 1024
#define STAGE_CAP 8192    // phase-D LDS staging capacity (32KB of u32)

// ---------------- Phase A: per-block bucket histograms ----------------------

__global__ __launch_bounds__(256) void bucket_hist_kernel(
    const int* __restrict__ rows0, int n0,
    const int* __restrict__ rows1, int n1,
    const int* __restrict__ rows2, int n2,
    int* __restrict__ hist_part,        // [3][NBLK][NB]
    int NB, int NBLK)
{
    int m = blockIdx.y;
    const int* rows = (m == 0) ? rows0 : (m == 1) ? rows1 : rows2;
    int nnz         = (m == 0) ? n0    : (m == 1) ? n1    : n2;
    __shared__ int bins[MAX_NB];
    if (threadIdx.x < NB) bins[threadIdx.x] = 0;
    __syncthreads();
    int base = blockIdx.x * EPB;
    #pragma unroll 4
    for (int k = 0; k < EPB / 256; ++k) {
        int i = base + k * 256 + threadIdx.x;
        if (i < nnz) atomicAdd(&bins[rows[i] >> RPB_SHIFT], 1);
    }
    __syncthreads();
    int* out = hist_part + ((size_t)(m * NBLK + blockIdx.x)) * NB;
    if (threadIdx.x < NB) out[threadIdx.x] = bins[threadIdx.x];
}

// ---------------- Phase B1: wave-per-(m,bucket) scan over blocks ------------

__global__ __launch_bounds__(256) void scan_blocks_wave_kernel(
    int* __restrict__ hist_part, int* __restrict__ totals, int NB, int NBLK)
{
    int w = blockIdx.x * 4 + (threadIdx.x >> 6);
    if (w >= 3 * NB) return;
    int lane = threadIdx.x & 63;
    int m = w / NB, b = w - m * NB;
    const int chunk = (NBLK + 63) >> 6;
    int base_blk = lane * chunk;

    int v[MAX_CHUNK];
    int sum = 0;
    for (int k = 0; k < chunk; ++k) {
        int blk = base_blk + k;
        int x = (blk < NBLK) ? hist_part[((size_t)(m * NBLK + blk)) * NB + b] : 0;
        v[k] = x; sum += x;
    }
    int incl = sum;
    #pragma unroll
    for (int s = 1; s < 64; s <<= 1) {
        int y = __shfl_up(incl, s);
        if (lane >= s) incl += y;
    }
    int run = incl - sum;                 // lane-exclusive prefix
    for (int k = 0; k < chunk; ++k) {
        int blk = base_blk + k;
        if (blk < NBLK) {
            hist_part[((size_t)(m * NBLK + blk)) * NB + b] = run;
            run += v[k];
        }
    }
    if (lane == 63) totals[w] = incl;
}

// ---------------- Phase B2: exclusive scan over buckets per matrix ----------

__global__ __launch_bounds__(1024) void scan_buckets_kernel(
    const int* __restrict__ totals, int* __restrict__ bases, int NB)
{
    int m = blockIdx.x;
    int t = threadIdx.x;
    int x = (t < NB) ? totals[m * NB + t] : 0;
    int lane = t & 63, wid = t >> 6;
    int incl = x;
    #pragma unroll
    for (int s = 1; s < 64; s <<= 1) {
        int y = __shfl_up(incl, s);
        if (lane >= s) incl += y;
    }
    __shared__ int wtot[16];
    __shared__ int wbase[16];
    if (lane == 63) wtot[wid] = incl;
    __syncthreads();
    if (t == 0) {
        int run = 0;
        #pragma unroll
        for (int w = 0; w < 16; ++w) { int v = wtot[w]; wbase[w] = run; run += v; }
    }
    __syncthreads();
    if (t < NB) bases[m * NB + t] = wbase[wid] + incl - x;
}

// ---------------- Phase C: LDS-staged bucket scatter ------------------------

__global__ __launch_bounds__(256) void bucket_scatter_kernel(
    const int* __restrict__ rows0, const int* __restrict__ cols0, const float* __restrict__ vals0, int n0,
    const int* __restrict__ rows1, const int* __restrict__ cols1, const float* __restrict__ vals1, int n1,
    const int* __restrict__ rows2, const int* __restrict__ cols2, const float* __restrict__ vals2, int n2,
    const float* __restrict__ theta,
    const int* __restrict__ hist_part, const int* __restrict__ bases,
    int2* __restrict__ eb0, int2* __restrict__ eb1, int2* __restrict__ eb2,
    int NB, int NBLK)
{
    int m = blockIdx.y;
    const int* rows; const int* cols; const float* vals; int nnz; int2* eb;
    if (m == 0)      { rows = rows0; cols = cols0; vals = vals0; nnz = n0; eb = eb0; }
    else if (m == 1) { rows = rows1; cols = cols1; vals = vals1; nnz = n1; eb = eb1; }
    else             { rows = rows2; cols = cols2; vals = vals2; nnz = n2; eb = eb2; }

    __shared__ int2 staged[EPB];               // 32 KB
    __shared__ unsigned char bucket_of[EPB];   // 4 KB
    __shared__ int lhist[MAX_NB];
    __shared__ int lstart[MAX_NB + 1];
    __shared__ int lcur[MAX_NB];
    __shared__ int gbase[MAX_NB];
    __shared__ int wtot[4], wbase[4];

    int t = threadIdx.x;
    if (t < NB) lhist[t] = 0;
    __syncthreads();

    int base = blockIdx.x * EPB;
    bool fold = (m == 2);

    int  bk[EPT];
    int2 pl[EPT];
    #pragma unroll
    for (int k = 0; k < EPT; ++k) {
        int i = base + k * 256 + t;
        if (i < nnz) {
            int r = rows[i], c = cols[i];
            float v = vals[i];
            if (fold) v *= theta[c];
            bk[k] = r >> RPB_SHIFT;
            pl[k] = make_int2(c | ((r & (RPB - 1)) << 16), __float_as_int(v));
            atomicAdd(&lhist[bk[k]], 1);
        } else bk[k] = -1;
    }
    __syncthreads();

    {   // block exclusive scan of NB (<=256) counts
        int x = (t < NB) ? lhist[t] : 0;
        int lane = t & 63, wid = t >> 6;
        int incl = x;
        #pragma unroll
        for (int s = 1; s < 64; s <<= 1) {
            int y = __shfl_up(incl, s);
            if (lane >= s) incl += y;
        }
        if (lane == 63) wtot[wid] = incl;
        __syncthreads();
        if (t == 0) {
            int run = 0;
            #pragma unroll
            for (int w = 0; w < 4; ++w) { int v = wtot[w]; wbase[w] = run; run += v; }
            lstart[MAX_NB] = run;
        }
        __syncthreads();
        if (t < NB) {
            int excl = wbase[wid] + incl - x;
            lstart[t] = excl;
            lcur[t]   = excl;
            const int* hp = hist_part + ((size_t)(m * NBLK + blockIdx.x)) * NB;
            gbase[t] = bases[m * NB + t] + hp[t];
        }
    }
    __syncthreads();

    #pragma unroll
    for (int k = 0; k < EPT; ++k) {
        if (bk[k] >= 0) {
            int idx = atomicAdd(&lcur[bk[k]], 1);     // LDS atomic
            staged[idx] = pl[k];
            bucket_of[idx] = (unsigned char)bk[k];
        }
    }
    __syncthreads();

    int count = min(EPB, nnz - base);
    for (int i = t; i < count; i += 256) {
        int b = bucket_of[i];
        int dest = gbase[b] + (i - lstart[b]);
        eb[dest] = staged[i];
    }
}

// ---------------- Phase D: bucket -> row-sorted COMPRESSED CSR + off --------
// Compressed edge: col(u16) | fp16(val)<<16. Output staged in LDS (row-
// sorted) then written sequentially coalesced; guarded direct-scatter
// fallback if a bucket exceeds STAGE_CAP.

__global__ __launch_bounds__(256) void bucket_to_csr_kernel(
    const int2* __restrict__ eb0, const int2* __restrict__ eb1, const int2* __restrict__ eb2,
    unsigned int* __restrict__ ec0, unsigned int* __restrict__ ec1, unsigned int* __restrict__ ec2,
    const int* __restrict__ bases,
    int* __restrict__ off,              // [3][n+1]
    int n0, int n1, int n2, int NB, int n)
{
    int m = blockIdx.y;
    int b = blockIdx.x;
    const int2* eb; unsigned int* ec; int nnz;
    if (m == 0)      { eb = eb0; ec = ec0; nnz = n0; }
    else if (m == 1) { eb = eb1; ec = ec1; nnz = n1; }
    else             { eb = eb2; ec = ec2; nnz = n2; }
    int base = bases[m * NB + b];
    int end  = (b + 1 < NB) ? bases[m * NB + b + 1] : nnz;
    int cnt  = end - base;

    __shared__ unsigned int staged_c[STAGE_CAP];   // 32 KB
    __shared__ int hist[RPB];
    __shared__ int cur[RPB];
    __shared__ int loc[RPB + 1];
    __shared__ int wtot[4];
    __shared__ int wbase[4];
    int t = threadIdx.x;
    hist[t] = 0; cur[t] = 0;
    __syncthreads();
    for (int i = base + t; i < end; i += 256)
        atomicAdd(&hist[(eb[i].x >> 16) & (RPB - 1)], 1);
    __syncthreads();
    {   // block exclusive scan of 256 counts
        int x = hist[t];
        int lane = t & 63, wid = t >> 6;
        int incl = x;
        #pragma unroll
        for (int s = 1; s < 64; s <<= 1) {
            int y = __shfl_up(incl, s);
            if (lane >= s) incl += y;
        }
        if (lane == 63) wtot[wid] = incl;
        __syncthreads();
        if (t == 0) {
            int run = 0;
            #pragma unroll
            for (int w = 0; w < 4; ++w) { int v = wtot[w]; wbase[w] = run; run += v; }
        }
        __syncthreads();
        loc[t] = wbase[wid] + incl - x;
        if (t == RPB - 1) loc[RPB] = wbase[3] + incl;
    }
    __syncthreads();
    {
        int r = b * RPB + t;
        if (r <= n) off[(size_t)m * (n + 1) + r] = base + loc[t];
        if (b == NB - 1 && t == 0) off[(size_t)m * (n + 1) + n] = nnz;
    }
    if (cnt <= STAGE_CAP) {
        // row-sort into LDS, then sequential coalesced writeback
        for (int i = base + t; i < end; i += 256) {
            int2 e = eb[i];
            int rl = (e.x >> 16) & (RPB - 1);
            int rk = atomicAdd(&cur[rl], 1);   // LDS atomic
            unsigned short h = __half_as_ushort(__float2half_rn(__int_as_float(e.y)));
            staged_c[loc[rl] + rk] = (unsigned int)(e.x & 0xFFFF) | ((unsigned int)h << 16);
        }
        __syncthreads();
        for (int i = t; i < cnt; i += 256)
            ec[base + i] = staged_c[i];
    } else {
        // oversized bucket: direct scatter (correctness path)
        for (int i = base + t; i < end; i += 256) {
            int2 e = eb[i];
            int rl = (e.x >> 16) & (RPB - 1);
            int rk = atomicAdd(&cur[rl], 1);
            unsigned short h = __half_as_ushort(__float2half_rn(__int_as_float(e.y)));
            ec[base + loc[rl] + rk] = (unsigned int)(e.x & 0xFFFF) | ((unsigned int)h << 16);
        }
    }
}

// ---------------- gather-side CSR SpMM, 4B compressed edges, unroll-8 -------

template<bool SRC_H, bool DST_H, bool RELU>
__global__ __launch_bounds__(256) void spmm_csr_kernel(
    const int* __restrict__ off, const unsigned int* __restrict__ edges,
    const void* __restrict__ dense_v, void* __restrict__ out_v, int nrows)
{
    int lane = threadIdx.x & 63;
    int r = blockIdx.x * 4 + (threadIdx.x >> 6);
    if (r >= nrows) return;
    int j   = __builtin_amdgcn_readfirstlane(off[r]);
    int end = __builtin_amdgcn_readfirstlane(off[r + 1]);
    const float2*  df = (const float2*)dense_v;
    const __half2* dh = (const __half2*)dense_v;

    float2 a0 = make_float2(0.f, 0.f), a1 = make_float2(0.f, 0.f);

    for (; j + 8 <= end; j += 8) {
        unsigned int e[8]; float2 d[8];
        #pragma unroll
        for (int k = 0; k < 8; ++k) e[k] = edges[j + k];
        #pragma unroll
        for (int k = 0; k < 8; ++k) {
            if (SRC_H) d[k] = __half22float2(dh[(size_t)(e[k] & 0xFFFF) * HALF_CH + lane]);
            else       d[k] = df[(size_t)(e[k] & 0xFFFF) * HALF_CH + lane];
        }
        #pragma unroll
        for (int k = 0; k < 8; ++k) {
            float v = __half2float(__ushort_as_half((unsigned short)(e[k] >> 16)));
            if (k & 1) { a1.x = fmaf(v, d[k].x, a1.x); a1.y = fmaf(v, d[k].y, a1.y); }
            else       { a0.x = fmaf(v, d[k].x, a0.x); a0.y = fmaf(v, d[k].y, a0.y); }
        }
    }
    for (; j + 4 <= end; j += 4) {
        unsigned int e[4]; float2 d[4];
        #pragma unroll
        for (int k = 0; k < 4; ++k) e[k] = edges[j + k];
        #pragma unroll
        for (int k = 0; k < 4; ++k) {
            if (SRC_H) d[k] = __half22float2(dh[(size_t)(e[k] & 0xFFFF) * HALF_CH + lane]);
            else       d[k] = df[(size_t)(e[k] & 0xFFFF) * HALF_CH + lane];
        }
        #pragma unroll
        for (int k = 0; k < 4; ++k) {
            float v = __half2float(__ushort_as_half((unsigned short)(e[k] >> 16)));
            if (k & 1) { a1.x = fmaf(v, d[k].x, a1.x); a1.y = fmaf(v, d[k].y, a1.y); }
            else       { a0.x = fmaf(v, d[k].x, a0.x); a0.y = fmaf(v, d[k].y, a0.y); }
        }
    }
    for (; j < end; ++j) {
        unsigned int e0 = edges[j];
        float2 d0;
        if (SRC_H) d0 = __half22float2(dh[(size_t)(e0 & 0xFFFF) * HALF_CH + lane]);
        else       d0 = df[(size_t)(e0 & 0xFFFF) * HALF_CH + lane];
        float v0 = __half2float(__ushort_as_half((unsigned short)(e0 >> 16)));
        a0.x = fmaf(v0, d0.x, a0.x); a0.y = fmaf(v0, d0.y, a0.y);
    }
    float2 res = make_float2(a0.x + a1.x, a0.y + a1.y);
    if (RELU) { res.x = fmaxf(res.x, 0.f); res.y = fmaxf(res.y, 0.f); }
    if (DST_H) ((__half2*)out_v)[(size_t)r * HALF_CH + lane] = __float22half2_rn(res);
    else       ((float2*) out_v)[(size_t)r * HALF_CH + lane] = res;
}

// ---------------- fallback (round-0) atomic path ----------------

__global__ __launch_bounds__(256) void spmm_atomic_kernel(
    const int* __restrict__ rows, const int* __restrict__ cols,
    const float* __restrict__ vals, const float* __restrict__ theta,
    const float* __restrict__ dense, float* __restrict__ out, int nnz)
{
    int idx = blockIdx.x * blockDim.x + threadIdx.x;
    int e = idx >> 7;
    int f = idx & (OUT_CH - 1);
    if (e >= nnz) return;
    int r = rows[e];
    int c = cols[e];
    float v = vals[e];
    if (theta != nullptr) v *= theta[c];
    atomicAdd(&out[(size_t)r * OUT_CH + f], v * dense[(size_t)c * OUT_CH + f]);
}

__global__ __launch_bounds__(256) void relu_kernel(float* __restrict__ out, int n4)
{
    int i = blockIdx.x * blockDim.x + threadIdx.x;
    if (i >= n4) return;
    float4 v = ((float4*)out)[i];
    v.x = fmaxf(v.x, 0.f); v.y = fmaxf(v.y, 0.f);
    v.z = fmaxf(v.z, 0.f); v.w = fmaxf(v.w, 0.f);
    ((float4*)out)[i] = v;
}

// ---------------- launch ----------------

static inline size_t align16(size_t x) { return (x + 15) & ~(size_t)15; }

extern "C" void kernel_launch(void* const* d_in, const int* in_sizes, int n_in,
                              void* d_out, int out_size, void* d_ws, size_t ws_size,
                              hipStream_t stream)
{
    const int*   phi_idx   = (const int*)d_in[0];
    const float* phi_vals  = (const float*)d_in[1];
    const int*   phii_idx  = (const int*)d_in[2];
    const float* phii_vals = (const float*)d_in[3];
    const int*   feat_idx  = (const int*)d_in[4];
    const float* feat_vals = (const float*)d_in[5];
    const float* W         = (const float*)d_in[6];
    const float* theta     = (const float*)d_in[7];

    const int nnz_phi  = in_sizes[1];
    const int nnz_phii = in_sizes[3];
    const int nnz_feat = in_sizes[5];
    const int n_nodes  = in_sizes[7];
    const int in_ch    = in_sizes[6] / OUT_CH;
    const size_t dense_elems = (size_t)n_nodes * OUT_CH;
    const long long total_e = (long long)nnz_feat + nnz_phii + nnz_phi;

    const int NB = (n_nodes + RPB - 1) >> RPB_SHIFT;
    int max_nnz = nnz_feat > nnz_phii ? nnz_feat : nnz_phii;
    if (nnz_phi > max_nnz) max_nnz = nnz_phi;
    const int NBLK = (max_nnz + EPB - 1) / EPB;

    // ---- workspace layout ----
    size_t p = 0;
    size_t filtered_off = p; p += align16(dense_elems * sizeof(__half));
    size_t tmp_off      = p; p += align16(dense_elems * sizeof(__half));
    size_t off_off      = p; p += align16((size_t)3 * (n_nodes + 1) * sizeof(int));
    size_t hp_off       = p; p += align16((size_t)3 * NBLK * NB * sizeof(int));
    size_t tot_off      = p; p += align16((size_t)3 * NB * sizeof(int));
    size_t bas_off      = p; p += align16((size_t)3 * NB * sizeof(int));
    size_t eb_off       = p; p += align16((size_t)total_e * sizeof(int2));
    size_t ec_off       = p; p += align16((size_t)total_e * sizeof(unsigned int));
    size_t need = p;

    char* ws = (char*)d_ws;
    dim3 block(256);

    bool fast_ok = (ws_size >= need) && (NB <= MAX_NB) && (n_nodes <= 65536) &&
                   (in_ch <= 65536) && (NBLK <= 64 * MAX_CHUNK);

    if (fast_ok) {
        __half* filtered = (__half*)(ws + filtered_off);
        __half* tmp      = (__half*)(ws + tmp_off);
        int* off_arr    = (int*)(ws + off_off);
        int* hist_part  = (int*)(ws + hp_off);
        int* totals     = (int*)(ws + tot_off);
        int* bases      = (int*)(ws + bas_off);
        int2* eb0 = (int2*)(ws + eb_off);
        int2* eb1 = eb0 + nnz_feat;
        int2* eb2 = eb1 + nnz_phii;
        unsigned int* ec0 = (unsigned int*)(ws + ec_off);
        unsigned int* ec1 = ec0 + nnz_feat;
        unsigned int* ec2 = ec1 + nnz_phii;

        const int* rows0 = feat_idx;  const int* cols0 = feat_idx + nnz_feat;
        const int* rows1 = phii_idx;  const int* cols1 = phii_idx + nnz_phii;
        const int* rows2 = phi_idx;   const int* cols2 = phi_idx  + nnz_phi;

        bucket_hist_kernel<<<dim3(NBLK, 3), block, 0, stream>>>(
            rows0, nnz_feat, rows1, nnz_phii, rows2, nnz_phi,
            hist_part, NB, NBLK);

        int nwaves = 3 * NB;
        scan_blocks_wave_kernel<<<dim3((nwaves + 3) / 4), block, 0, stream>>>(
            hist_part, totals, NB, NBLK);

        scan_buckets_kernel<<<dim3(3), dim3(1024), 0, stream>>>(totals, bases, NB);

        bucket_scatter_kernel<<<dim3(NBLK, 3), block, 0, stream>>>(
            rows0, cols0, feat_vals, nnz_feat,
            rows1, cols1, phii_vals, nnz_phii,
            rows2, cols2, phi_vals,  nnz_phi,
            theta, hist_part, bases, eb0, eb1, eb2, NB, NBLK);

        bucket_to_csr_kernel<<<dim3(NB, 3), block, 0, stream>>>(
            eb0, eb1, eb2, ec0, ec1, ec2, bases, off_arr,
            nnz_feat, nnz_phii, nnz_phi, NB, n_nodes);

        int* off_f  = off_arr;
        int* off_pi = off_arr + (n_nodes + 1);
        int* off_p  = off_arr + 2 * (n_nodes + 1);

        dim3 grid_r((unsigned)((n_nodes + 3) / 4));
        // stage 1: src fp32 W, dst fp16 filtered
        spmm_csr_kernel<false, true, false><<<grid_r, block, 0, stream>>>(
            off_f,  ec0, (const void*)W, (void*)filtered, n_nodes);
        // stage 2: src fp16 filtered, dst fp16 tmp
        spmm_csr_kernel<true, true, false><<<grid_r, block, 0, stream>>>(
            off_pi, ec1, (const void*)filtered, (void*)tmp, n_nodes);
        // stage 3: src fp16 tmp, dst fp32 out + relu
        spmm_csr_kernel<true, false, true><<<grid_r, block, 0, stream>>>(
            off_p,  ec2, (const void*)tmp, d_out, n_nodes);
    } else {
        // fallback: round-0 atomic path (needs only 2 fp32 dense buffers)
        float* filtered = (float*)ws;
        float* tmp      = filtered + dense_elems;
        hipMemsetAsync(filtered, 0, 2 * dense_elems * sizeof(float), stream);
        hipMemsetAsync(d_out, 0, (size_t)out_size * sizeof(float), stream);
        {
            long long t = (long long)nnz_feat * OUT_CH;
            spmm_atomic_kernel<<<dim3((unsigned)((t + 255) / 256)), block, 0, stream>>>(
                feat_idx, feat_idx + nnz_feat, feat_vals, nullptr, W, filtered, nnz_feat);
        }
        {
            long long t = (long long)nnz_phii * OUT_CH;
            spmm_atomic_kernel<<<dim3((unsigned)((t + 255) / 256)), block, 0, stream>>>(
                phii_idx, phii_idx + nnz_phii, phii_vals, nullptr, filtered, tmp, nnz_phii);
        }
        {
            long long t = (long long)nnz_phi * OUT_CH;
            spmm_atomic_kernel<<<dim3((unsigned)((t + 255) / 256)), block, 0, stream>>>(
                phi_idx, phi_idx + nnz_phi, phi_vals, theta, tmp, (float*)d_out, nnz_phi);
        }
        {
            int n4 = out_size / 4;
            relu_kernel<<<dim3((n4 + 255) / 256), block, 0, stream>>>((float*)d_out, n4);
        }
    }
}